// Round 5
// baseline (150.407 us; speedup 1.0000x reference)
//
#include <hip/hip_runtime.h>
#include <hip/hip_bf16.h>

#define WIN 7
#define SHIFT_SZ 3
#define WSQ 49
#define CH 128
#define HW 56
#define LOG2E 1.4426950408889634f
#define QSCALE (0.17677669529663687f * LOG2E)

typedef short s16x8 __attribute__((ext_vector_type(8)));
typedef short s16x4 __attribute__((ext_vector_type(4)));
typedef float f32x4 __attribute__((ext_vector_type(4)));

static __device__ __forceinline__ f32x4 mfma16(s16x4 a, s16x4 b, f32x4 c) {
#if __has_builtin(__builtin_amdgcn_mfma_f32_16x16x16bf16_1k)
  return __builtin_amdgcn_mfma_f32_16x16x16bf16_1k(a, b, c, 0, 0, 0);
#else
  f32x4 d;
  asm("v_mfma_f32_16x16x16_bf16 %0, %1, %2, %3" : "=v"(d) : "v"(a), "v"(b), "v"(c));
  return d;
#endif
}

// ---------------- prep kernels ----------------

__global__ void prep_weights(const float* __restrict__ qkv_kernel,
                             const float* __restrict__ proj_kernel,
                             __hip_bfloat16* __restrict__ ws) {
  int idx = blockIdx.x * 256 + threadIdx.x;
  if (idx < 49152) {                      // WqkvT [384][128]
    int n = idx >> 7, c = idx & 127;
    ws[idx] = __float2bfloat16(qkv_kernel[c * 384 + n]);
  }
  if (idx < 16384) {                      // WprojT [128][128]
    int n = idx >> 7, c = idx & 127;
    ws[49152 + idx] = __float2bfloat16(proj_kernel[c * 128 + n]);
  }
}

// tbl[win][h][s][t] = LOG2E * (rel_pos_bias(s,t) + shift_mask(s,t));
// cols t>=49 -> -43280 (kills padded keys), rows s>=49 (dead queries) -> 0
__global__ void prep_tbl(const float* __restrict__ rel_pos_table,
                         __hip_bfloat16* __restrict__ tbl) {
  int idx = blockIdx.x * 256 + threadIdx.x;   // 2^20 total
  int t = idx & 63;
  int s = (idx >> 6) & 63;
  int h = (idx >> 12) & 3;
  int win = idx >> 14;
  float v;
  if (t >= WSQ) v = -43280.f;
  else if (s >= WSQ) v = 0.f;
  else {
    int i1 = s / 7, j1 = s % 7, i2 = t / 7, j2 = t % 7;
    int ridx = (i1 - i2 + 6) * 13 + (j1 - j2 + 6);
    float bias = rel_pos_table[ridx * 4 + h];
    int wy = win >> 3, wx = win & 7;
    int rh1 = (wy < 7) ? 0 : (i1 < 4 ? 1 : 2);
    int rh2 = (wy < 7) ? 0 : (i2 < 4 ? 1 : 2);
    int rw1 = (wx < 7) ? 0 : (j1 < 4 ? 1 : 2);
    int rw2 = (wx < 7) ? 0 : (j2 < 4 ? 1 : 2);
    float mask = (rh1 == rh2 && rw1 == rw2) ? 0.f : -100.f;
    v = (bias + mask) * LOG2E;
  }
  tbl[idx] = __float2bfloat16(v);
}

// ---------------- fused main kernel ----------------
// one block = one window (4096 blocks), 512 threads = 8 waves.
// LDS 35840 B -> 4 blocks/CU. Regions (time-multiplexed):
//   [0,17408)      x-stage [64][136]; later vt [4][32][64] (4-elem-blk swz)
//   [17408,35840)  k [4][64][36];     later o  [64][136]
// Q and P never touch LDS (16x16x16 MFMA consumes producer acc layout).
// Barriers: b1 x staged | b2 a_lds reads done, k visible | b3 vt visible,
//           k reads done | b4 o visible.
// Register discipline (spill-free under the 64/lane cap of (512,8)):
//   Q-pass acc 8 f32, PV oacc 8 f32 (per-half completion), K/V acc 16 f32.

__launch_bounds__(512, 8)
__global__ void swin_attn(const float* __restrict__ x,
                          const float* __restrict__ qkv_bias,
                          const float* __restrict__ proj_bias,
                          const __hip_bfloat16* __restrict__ wqkvT,
                          const __hip_bfloat16* __restrict__ wprojT,
                          const __hip_bfloat16* __restrict__ tbl,
                          float* __restrict__ out) {
  __shared__ __align__(16) char smem[35840];
  __hip_bfloat16* a_lds  = (__hip_bfloat16*)smem;             // [64][136]
  __hip_bfloat16* vt_lds = (__hip_bfloat16*)smem;             // [4][32][64] swz
  __hip_bfloat16* k_lds  = (__hip_bfloat16*)(smem + 17408);   // [4][64][36]
  __hip_bfloat16* o_lds  = (__hip_bfloat16*)(smem + 17408);   // [64][136]

  const int tid = threadIdx.x;
  const int lane = tid & 63;
  const int wv = tid >> 6;          // wave 0..7
  const int g = lane >> 4;          // quarter-wave group
  const int c = lane & 15;

  const int widx = blockIdx.x;
  const int b  = widx >> 6;
  const int wy = (widx >> 3) & 7;
  const int wx = widx & 7;
  const int win64 = widx & 63;

  const int h3 = wv >> 1;           // attention head of this wave
  const int mh = wv & 1;            // s-half (rows 32*mh..32*mh+31)

  // ---- phase 1: stage shifted x-window as bf16 (rows 49..63 zero) ----
  for (int it = tid; it < 1024; it += 512) {
    int s = it >> 4;
    int l16 = it & 15;
    union { s16x8 v; __hip_bfloat16 h[8]; } u;
    if (s < WSQ) {
      int i = s / 7, j = s - i * 7;
      int hh = wy * 7 + i + SHIFT_SZ; if (hh >= HW) hh -= HW;
      int ww = wx * 7 + j + SHIFT_SZ; if (ww >= HW) ww -= HW;
      const float4* src = (const float4*)(x + (((b * HW + hh) * HW + ww) * CH + l16 * 8));
      float4 f0 = src[0], f1 = src[1];
      u.h[0] = __float2bfloat16(f0.x); u.h[1] = __float2bfloat16(f0.y);
      u.h[2] = __float2bfloat16(f0.z); u.h[3] = __float2bfloat16(f0.w);
      u.h[4] = __float2bfloat16(f1.x); u.h[5] = __float2bfloat16(f1.y);
      u.h[6] = __float2bfloat16(f1.z); u.h[7] = __float2bfloat16(f1.w);
    } else {
      #pragma unroll
      for (int q = 0; q < 8; ++q) u.h[q] = __float2bfloat16(0.f);
    }
    *(s16x8*)(a_lds + s * 136 + l16 * 8) = u.v;
  }
  __syncthreads();   // b1

  // ---- K-pass: wave wv computes K n-tile (8+wv), n-major; scatter to k_lds
  {
    f32x4 acc[4];
    #pragma unroll
    for (int mt = 0; mt < 4; ++mt) acc[mt] = (f32x4){0.f, 0.f, 0.f, 0.f};
    #pragma unroll
    for (int kt = 0; kt < 4; ++kt) {
      s16x8 bf = *(const s16x8*)(wqkvT + (16 * (8 + wv) + c) * 128 + kt * 32 + g * 8);
      #pragma unroll
      for (int mt = 0; mt < 4; ++mt) {
        s16x8 af = *(const s16x8*)(a_lds + (16 * mt + c) * 136 + kt * 32 + g * 8);
        acc[mt] = __builtin_amdgcn_mfma_f32_16x16x32_bf16(bf, af, acc[mt], 0, 0, 0);
      }
    }
    float4 kb4 = *(const float4*)(qkv_bias + 128 + 16 * wv + 4 * g);
    __hip_bfloat16* dst = k_lds + (wv >> 1) * 2304 + (wv & 1) * 16 + 4 * g;
    #pragma unroll
    for (int mt = 0; mt < 4; ++mt) {
      union { s16x4 v; __hip_bfloat16 h[4]; } u;
      u.h[0] = __float2bfloat16(acc[mt][0] + kb4.x);
      u.h[1] = __float2bfloat16(acc[mt][1] + kb4.y);
      u.h[2] = __float2bfloat16(acc[mt][2] + kb4.z);
      u.h[3] = __float2bfloat16(acc[mt][3] + kb4.w);
      *(s16x4*)(dst + (16 * mt + c) * 36) = u.v;
    }
  }

  // ---- V-pass: wave wv computes V n-tile (16+wv), m-major; hold packed ----
  s16x4 vheld[4];
  {
    f32x4 acc[4];
    #pragma unroll
    for (int mt = 0; mt < 4; ++mt) acc[mt] = (f32x4){0.f, 0.f, 0.f, 0.f};
    #pragma unroll
    for (int kt = 0; kt < 4; ++kt) {
      s16x8 bv = *(const s16x8*)(wqkvT + (16 * (16 + wv) + c) * 128 + kt * 32 + g * 8);
      #pragma unroll
      for (int mt = 0; mt < 4; ++mt) {
        s16x8 af = *(const s16x8*)(a_lds + (16 * mt + c) * 136 + kt * 32 + g * 8);
        acc[mt] = __builtin_amdgcn_mfma_f32_16x16x32_bf16(af, bv, acc[mt], 0, 0, 0);
      }
    }
    float vb = qkv_bias[256 + 16 * wv + c];
    #pragma unroll
    for (int mt = 0; mt < 4; ++mt) {
      union { s16x4 v; __hip_bfloat16 h[4]; } u;
      #pragma unroll
      for (int r = 0; r < 4; ++r) u.h[r] = __float2bfloat16(acc[mt][r] + vb);
      vheld[mt] = u.v;
    }
  }

  // ---- Q-pass: own Q (head h3, s-half mh), n-major; ntl OUTER (acc=8) ----
  s16x4 qf16[2][2];   // [kb(=d 16-block)][m]
  #pragma unroll
  for (int ntl = 0; ntl < 2; ++ntl) {
    f32x4 acc[2];
    acc[0] = (f32x4){0.f, 0.f, 0.f, 0.f};
    acc[1] = (f32x4){0.f, 0.f, 0.f, 0.f};
    #pragma unroll
    for (int kt = 0; kt < 4; ++kt) {
      s16x8 bf = *(const s16x8*)(wqkvT + (16 * (2 * h3 + ntl) + c) * 128 + kt * 32 + g * 8);
      #pragma unroll
      for (int m = 0; m < 2; ++m) {
        s16x8 af = *(const s16x8*)(a_lds + (16 * (2 * mh + m) + c) * 136 + kt * 32 + g * 8);
        acc[m] = __builtin_amdgcn_mfma_f32_16x16x32_bf16(bf, af, acc[m], 0, 0, 0);
      }
    }
    float4 qb4 = *(const float4*)(qkv_bias + 32 * h3 + 16 * ntl + 4 * g);
    #pragma unroll
    for (int m = 0; m < 2; ++m) {
      union { s16x4 v; __hip_bfloat16 h[4]; } u;
      u.h[0] = __float2bfloat16((acc[m][0] + qb4.x) * QSCALE);
      u.h[1] = __float2bfloat16((acc[m][1] + qb4.y) * QSCALE);
      u.h[2] = __float2bfloat16((acc[m][2] + qb4.z) * QSCALE);
      u.h[3] = __float2bfloat16((acc[m][3] + qb4.w) * QSCALE);
      qf16[ntl][m] = u.v;
    }
  }
  __syncthreads();   // b2: a_lds reads done; k_lds visible

  // ---- vt scatter into (dead) x region: [4][32][64], 4-elem-blk XOR swz ----
  {
    int row = (wv >> 1) * 32 + (wv & 1) * 16 + c;   // row&15 == c
    #pragma unroll
    for (int mt = 0; mt < 4; ++mt) {
      int tb = (4 * mt + g) ^ c;
      *(s16x4*)(vt_lds + row * 64 + tb * 4) = vheld[mt];
    }
  }

  // ---- QK^T (x16 MFMA, kf from LDS, qf from regs) + in-reg softmax ----
  s16x4 pf16[2][4];   // [m][nt] : P row s=lane-c(+16m+32mh), t=16nt+4g+{0..3}
  #pragma unroll
  for (int m = 0; m < 2; ++m) {
    f32x4 sc[4];
    #pragma unroll
    for (int nt = 0; nt < 4; ++nt) {
      sc[nt] = (f32x4){0.f, 0.f, 0.f, 0.f};
      #pragma unroll
      for (int kb = 0; kb < 2; ++kb) {
        s16x4 kf = *(const s16x4*)(k_lds + h3 * 2304 + (16 * nt + c) * 36 + 16 * kb + 4 * g);
        sc[nt] = mfma16(kf, qf16[kb][m], sc[nt]);
      }
    }
    const __hip_bfloat16* tb_ =
        tbl + (((win64 << 2) + h3) << 12) + (32 * mh + 16 * m + c) * 64;
    #pragma unroll
    for (int nt = 0; nt < 4; ++nt) {
      union { s16x4 v; __hip_bfloat16 h[4]; } tv;
      tv.v = *(const s16x4*)(tb_ + 16 * nt + 4 * g);
      #pragma unroll
      for (int r = 0; r < 4; ++r) sc[nt][r] += __bfloat162float(tv.h[r]);
    }
    float mx = -1e30f;
    #pragma unroll
    for (int nt = 0; nt < 4; ++nt)
      #pragma unroll
      for (int r = 0; r < 4; ++r) mx = fmaxf(mx, sc[nt][r]);
    mx = fmaxf(mx, __shfl_xor(mx, 16));
    mx = fmaxf(mx, __shfl_xor(mx, 32));
    float sum = 0.f;
    #pragma unroll
    for (int nt = 0; nt < 4; ++nt)
      #pragma unroll
      for (int r = 0; r < 4; ++r) {
        float e = __builtin_amdgcn_exp2f(sc[nt][r] - mx);
        sc[nt][r] = e;
        sum += e;
      }
    sum += __shfl_xor(sum, 16);
    sum += __shfl_xor(sum, 32);
    float inv = __builtin_amdgcn_rcpf(sum);
    #pragma unroll
    for (int nt = 0; nt < 4; ++nt) {
      union { s16x4 v; __hip_bfloat16 h[4]; } u;
      #pragma unroll
      for (int r = 0; r < 4; ++r) u.h[r] = __float2bfloat16(sc[nt][r] * inv);
      pf16[m][nt] = u.v;
    }
  }
  __syncthreads();   // b3: vt visible; all k reads done

  // ---- PV: O^T = V^T @ P^T (x16 MFMA); per-ntd completion (oacc=8) ----
  #pragma unroll
  for (int ntd = 0; ntd < 2; ++ntd) {
    s16x4 vf16[4];
    #pragma unroll
    for (int nt = 0; nt < 4; ++nt) {
      int row = h3 * 32 + 16 * ntd + c;               // row&15 == c
      int tb = (4 * nt + g) ^ c;
      vf16[nt] = *(const s16x4*)(vt_lds + row * 64 + tb * 4);
    }
    #pragma unroll
    for (int m = 0; m < 2; ++m) {
      f32x4 oacc = (f32x4){0.f, 0.f, 0.f, 0.f};
      #pragma unroll
      for (int nt = 0; nt < 4; ++nt)
        oacc = mfma16(vf16[nt], pf16[m][nt], oacc);
      union { s16x4 v; __hip_bfloat16 h[4]; } u;
      #pragma unroll
      for (int r = 0; r < 4; ++r) u.h[r] = __float2bfloat16(oacc[r]);
      *(s16x4*)(o_lds + (32 * mh + 16 * m + c) * 136 + 32 * h3 + 16 * ntd + 4 * g) = u.v;
    }
  }
  __syncthreads();   // b4: o visible

  // ---- proj GEMM (n-major out -> float4 stores). wave owns n-tile wv ----
  {
    f32x4 pacc[4];
    #pragma unroll
    for (int mt = 0; mt < 4; ++mt) pacc[mt] = (f32x4){0.f, 0.f, 0.f, 0.f};
    #pragma unroll
    for (int kt = 0; kt < 4; ++kt) {
      s16x8 bfp = *(const s16x8*)(wprojT + (16 * wv + c) * 128 + kt * 32 + g * 8);
      #pragma unroll
      for (int mt = 0; mt < 4; ++mt) {
        s16x8 afo = *(const s16x8*)(o_lds + (16 * mt + c) * 136 + kt * 32 + g * 8);
        pacc[mt] = __builtin_amdgcn_mfma_f32_16x16x32_bf16(bfp, afo, pacc[mt], 0, 0, 0);
      }
    }
    float4 pb4 = *(const float4*)(proj_bias + 16 * wv + 4 * g);
    #pragma unroll
    for (int mt = 0; mt < 4; ++mt) {
      int s = 16 * mt + c;
      if (s < WSQ) {
        int i = s / 7, j = s - i * 7;
        int hh = wy * 7 + i + SHIFT_SZ; if (hh >= HW) hh -= HW;
        int ww = wx * 7 + j + SHIFT_SZ; if (ww >= HW) ww -= HW;
        float4 v;
        v.x = pacc[mt][0] + pb4.x;
        v.y = pacc[mt][1] + pb4.y;
        v.z = pacc[mt][2] + pb4.z;
        v.w = pacc[mt][3] + pb4.w;
        *(float4*)(out + ((b * HW + hh) * HW + ww) * CH + 16 * wv + 4 * g) = v;
      }
    }
  }
}

extern "C" void kernel_launch(void* const* d_in, const int* in_sizes, int n_in,
                              void* d_out, int out_size, void* d_ws, size_t ws_size,
                              hipStream_t stream) {
  const float* x            = (const float*)d_in[0];
  const float* qkv_kernel   = (const float*)d_in[1];
  const float* qkv_bias     = (const float*)d_in[2];
  const float* proj_kernel  = (const float*)d_in[3];
  const float* proj_bias    = (const float*)d_in[4];
  const float* rel_pos_tbl  = (const float*)d_in[5];
  float* out = (float*)d_out;

  __hip_bfloat16* wsb    = (__hip_bfloat16*)d_ws;
  __hip_bfloat16* wqkvT  = wsb;            // 49152 elems
  __hip_bfloat16* wprojT = wsb + 49152;    // 16384 elems
  __hip_bfloat16* tbl    = wsb + 65536;    // 1048576 elems

  prep_weights<<<dim3(192), dim3(256), 0, stream>>>(qkv_kernel, proj_kernel, wsb);
  prep_tbl<<<dim3(4096), dim3(256), 0, stream>>>(rel_pos_tbl, tbl);
  swin_attn<<<dim3(4096), dim3(512), 0, stream>>>(x, qkv_bias, proj_bias,
                                                  wqkvT, wprojT, tbl, out);
}

// Round 7
// 140.863 us; speedup vs baseline: 1.0678x; 1.0678x over previous
//
#include <hip/hip_runtime.h>
#include <hip/hip_bf16.h>

#define WIN 7
#define SHIFT_SZ 3
#define WSQ 49
#define CH 128
#define HW 56
#define LOG2E 1.4426950408889634f
#define QSCALE (0.17677669529663687f * LOG2E)

typedef short s16x8 __attribute__((ext_vector_type(8)));
typedef short s16x4 __attribute__((ext_vector_type(4)));
typedef float f32x4 __attribute__((ext_vector_type(4)));

static __device__ __forceinline__ f32x4 mfma16(s16x4 a, s16x4 b, f32x4 c) {
#if __has_builtin(__builtin_amdgcn_mfma_f32_16x16x16bf16_1k)
  return __builtin_amdgcn_mfma_f32_16x16x16bf16_1k(a, b, c, 0, 0, 0);
#else
  f32x4 d;
  asm("v_mfma_f32_16x16x16_bf16 %0, %1, %2, %3" : "=v"(d) : "v"(a), "v"(b), "v"(c));
  return d;
#endif
}

// ---------------- prep kernels ----------------

__global__ void prep_weights(const float* __restrict__ qkv_kernel,
                             const float* __restrict__ proj_kernel,
                             __hip_bfloat16* __restrict__ ws) {
  int idx = blockIdx.x * 256 + threadIdx.x;
  if (idx < 49152) {                      // WqkvT [384][128]
    int n = idx >> 7, c = idx & 127;
    ws[idx] = __float2bfloat16(qkv_kernel[c * 384 + n]);
  }
  if (idx < 16384) {                      // WprojT [128][128]
    int n = idx >> 7, c = idx & 127;
    ws[49152 + idx] = __float2bfloat16(proj_kernel[c * 128 + n]);
  }
}

// tbl[win][h][s][t] = LOG2E * (rel_pos_bias(s,t) + shift_mask(s,t));
// cols t>=49 -> -43280 (kills padded keys), rows s>=49 (dead queries) -> 0
__global__ void prep_tbl(const float* __restrict__ rel_pos_table,
                         __hip_bfloat16* __restrict__ tbl) {
  int idx = blockIdx.x * 256 + threadIdx.x;   // 2^20 total
  int t = idx & 63;
  int s = (idx >> 6) & 63;
  int h = (idx >> 12) & 3;
  int win = idx >> 14;
  float v;
  if (t >= WSQ) v = -43280.f;
  else if (s >= WSQ) v = 0.f;
  else {
    int i1 = s / 7, j1 = s % 7, i2 = t / 7, j2 = t % 7;
    int ridx = (i1 - i2 + 6) * 13 + (j1 - j2 + 6);
    float bias = rel_pos_table[ridx * 4 + h];
    int wy = win >> 3, wx = win & 7;
    int rh1 = (wy < 7) ? 0 : (i1 < 4 ? 1 : 2);
    int rh2 = (wy < 7) ? 0 : (i2 < 4 ? 1 : 2);
    int rw1 = (wx < 7) ? 0 : (j1 < 4 ? 1 : 2);
    int rw2 = (wx < 7) ? 0 : (j2 < 4 ? 1 : 2);
    float mask = (rh1 == rh2 && rw1 == rw2) ? 0.f : -100.f;
    v = (bias + mask) * LOG2E;
  }
  tbl[idx] = __float2bfloat16(v);
}

// ---------------- fused main kernel ----------------
// one block = one window (4096 blocks), 512 threads = 8 waves.
// LDS 35840 B. Regions (time-multiplexed):
//   [0,17408)      x-stage [64][136]; later vt [4][32][64] (4-elem-blk swz)
//   [17408,35840)  k [4][64][36];     later o  [64][136]
// Q and P never touch LDS (16x16x16 MFMA consumes producer acc layout).
// Barriers: b1 x staged | b2 a_lds reads done, k visible | b3 vt visible,
//           k reads done | b4 o visible.
// Register budget: (512,6) -> ~85 regs/lane. (512,8)'s 64-reg cap is proven
// unreachable (R3/R4 spilled ~250MB); 6-7 waves/SIMD both give 3 blocks/CU,
// so 85 is the right spill-free target.

__launch_bounds__(512, 6)
__global__ void swin_attn(const float* __restrict__ x,
                          const float* __restrict__ qkv_bias,
                          const float* __restrict__ proj_bias,
                          const __hip_bfloat16* __restrict__ wqkvT,
                          const __hip_bfloat16* __restrict__ wprojT,
                          const __hip_bfloat16* __restrict__ tbl,
                          float* __restrict__ out) {
  __shared__ __align__(16) char smem[35840];
  __hip_bfloat16* a_lds  = (__hip_bfloat16*)smem;             // [64][136]
  __hip_bfloat16* vt_lds = (__hip_bfloat16*)smem;             // [4][32][64] swz
  __hip_bfloat16* k_lds  = (__hip_bfloat16*)(smem + 17408);   // [4][64][36]
  __hip_bfloat16* o_lds  = (__hip_bfloat16*)(smem + 17408);   // [64][136]

  const int tid = threadIdx.x;
  const int lane = tid & 63;
  const int wv = tid >> 6;          // wave 0..7
  const int g = lane >> 4;          // quarter-wave group
  const int c = lane & 15;

  const int widx = blockIdx.x;
  const int b  = widx >> 6;
  const int wy = (widx >> 3) & 7;
  const int wx = widx & 7;
  const int win64 = widx & 63;

  const int h3 = wv >> 1;           // attention head of this wave
  const int mh = wv & 1;            // s-half (rows 32*mh..32*mh+31)

  // ---- phase 1: stage shifted x-window as bf16 (rows 49..63 zero) ----
  for (int it = tid; it < 1024; it += 512) {
    int s = it >> 4;
    int l16 = it & 15;
    union { s16x8 v; __hip_bfloat16 h[8]; } u;
    if (s < WSQ) {
      int i = s / 7, j = s - i * 7;
      int hh = wy * 7 + i + SHIFT_SZ; if (hh >= HW) hh -= HW;
      int ww = wx * 7 + j + SHIFT_SZ; if (ww >= HW) ww -= HW;
      const float4* src = (const float4*)(x + (((b * HW + hh) * HW + ww) * CH + l16 * 8));
      float4 f0 = src[0], f1 = src[1];
      u.h[0] = __float2bfloat16(f0.x); u.h[1] = __float2bfloat16(f0.y);
      u.h[2] = __float2bfloat16(f0.z); u.h[3] = __float2bfloat16(f0.w);
      u.h[4] = __float2bfloat16(f1.x); u.h[5] = __float2bfloat16(f1.y);
      u.h[6] = __float2bfloat16(f1.z); u.h[7] = __float2bfloat16(f1.w);
    } else {
      #pragma unroll
      for (int q = 0; q < 8; ++q) u.h[q] = __float2bfloat16(0.f);
    }
    *(s16x8*)(a_lds + s * 136 + l16 * 8) = u.v;
  }
  __syncthreads();   // b1

  // ---- K-pass: wave wv computes K n-tile (8+wv), n-major; scatter to k_lds
  {
    f32x4 acc[4];
    #pragma unroll
    for (int mt = 0; mt < 4; ++mt) acc[mt] = (f32x4){0.f, 0.f, 0.f, 0.f};
    #pragma unroll
    for (int kt = 0; kt < 4; ++kt) {
      s16x8 bf = *(const s16x8*)(wqkvT + (16 * (8 + wv) + c) * 128 + kt * 32 + g * 8);
      #pragma unroll
      for (int mt = 0; mt < 4; ++mt) {
        s16x8 af = *(const s16x8*)(a_lds + (16 * mt + c) * 136 + kt * 32 + g * 8);
        acc[mt] = __builtin_amdgcn_mfma_f32_16x16x32_bf16(bf, af, acc[mt], 0, 0, 0);
      }
    }
    float4 kb4 = *(const float4*)(qkv_bias + 128 + 16 * wv + 4 * g);
    __hip_bfloat16* dst = k_lds + (wv >> 1) * 2304 + (wv & 1) * 16 + 4 * g;
    #pragma unroll
    for (int mt = 0; mt < 4; ++mt) {
      union { s16x4 v; __hip_bfloat16 h[4]; } u;
      u.h[0] = __float2bfloat16(acc[mt][0] + kb4.x);
      u.h[1] = __float2bfloat16(acc[mt][1] + kb4.y);
      u.h[2] = __float2bfloat16(acc[mt][2] + kb4.z);
      u.h[3] = __float2bfloat16(acc[mt][3] + kb4.w);
      *(s16x4*)(dst + (16 * mt + c) * 36) = u.v;
    }
  }

  // ---- V-pass: wave wv computes V n-tile (16+wv), m-major; hold packed ----
  s16x4 vheld[4];
  {
    f32x4 acc[4];
    #pragma unroll
    for (int mt = 0; mt < 4; ++mt) acc[mt] = (f32x4){0.f, 0.f, 0.f, 0.f};
    #pragma unroll
    for (int kt = 0; kt < 4; ++kt) {
      s16x8 bv = *(const s16x8*)(wqkvT + (16 * (16 + wv) + c) * 128 + kt * 32 + g * 8);
      #pragma unroll
      for (int mt = 0; mt < 4; ++mt) {
        s16x8 af = *(const s16x8*)(a_lds + (16 * mt + c) * 136 + kt * 32 + g * 8);
        acc[mt] = __builtin_amdgcn_mfma_f32_16x16x32_bf16(af, bv, acc[mt], 0, 0, 0);
      }
    }
    float vb = qkv_bias[256 + 16 * wv + c];
    #pragma unroll
    for (int mt = 0; mt < 4; ++mt) {
      union { s16x4 v; __hip_bfloat16 h[4]; } u;
      #pragma unroll
      for (int r = 0; r < 4; ++r) u.h[r] = __float2bfloat16(acc[mt][r] + vb);
      vheld[mt] = u.v;
    }
  }

  // ---- Q-pass: wave computes ITS OWN Q (head h3, s-half mh), n-major ----
  s16x4 qf16[2][2];   // [kb(=d 16-block)][m]
  {
    f32x4 acc[2][2];
    #pragma unroll
    for (int ntl = 0; ntl < 2; ++ntl)
      #pragma unroll
      for (int m = 0; m < 2; ++m) acc[ntl][m] = (f32x4){0.f, 0.f, 0.f, 0.f};
    #pragma unroll
    for (int kt = 0; kt < 4; ++kt) {
      s16x8 afq[2];
      #pragma unroll
      for (int m = 0; m < 2; ++m)
        afq[m] = *(const s16x8*)(a_lds + (16 * (2 * mh + m) + c) * 136 + kt * 32 + g * 8);
      #pragma unroll
      for (int ntl = 0; ntl < 2; ++ntl) {
        s16x8 bf = *(const s16x8*)(wqkvT + (16 * (2 * h3 + ntl) + c) * 128 + kt * 32 + g * 8);
        #pragma unroll
        for (int m = 0; m < 2; ++m)
          acc[ntl][m] = __builtin_amdgcn_mfma_f32_16x16x32_bf16(bf, afq[m], acc[ntl][m], 0, 0, 0);
      }
    }
    #pragma unroll
    for (int ntl = 0; ntl < 2; ++ntl) {
      float4 qb4 = *(const float4*)(qkv_bias + 32 * h3 + 16 * ntl + 4 * g);
      #pragma unroll
      for (int m = 0; m < 2; ++m) {
        union { s16x4 v; __hip_bfloat16 h[4]; } u;
        u.h[0] = __float2bfloat16((acc[ntl][m][0] + qb4.x) * QSCALE);
        u.h[1] = __float2bfloat16((acc[ntl][m][1] + qb4.y) * QSCALE);
        u.h[2] = __float2bfloat16((acc[ntl][m][2] + qb4.z) * QSCALE);
        u.h[3] = __float2bfloat16((acc[ntl][m][3] + qb4.w) * QSCALE);
        qf16[ntl][m] = u.v;
      }
    }
  }
  __syncthreads();   // b2: a_lds reads done; k_lds visible

  // ---- vt scatter into (dead) x region: [4][32][64], 4-elem-blk XOR swz ----
  {
    int row = (wv >> 1) * 32 + (wv & 1) * 16 + c;   // row&15 == c
    #pragma unroll
    for (int mt = 0; mt < 4; ++mt) {
      int tb = (4 * mt + g) ^ c;
      *(s16x4*)(vt_lds + row * 64 + tb * 4) = vheld[mt];
    }
  }

  // ---- QK^T (x16 MFMA, kf from LDS, qf from regs) + in-reg softmax ----
  s16x4 pf16[2][4];   // [m][nt] : P row s=lane-c(+16m+32mh), t=16nt+4g+{0..3}
  #pragma unroll
  for (int m = 0; m < 2; ++m) {
    f32x4 sc[4];
    #pragma unroll
    for (int nt = 0; nt < 4; ++nt) {
      sc[nt] = (f32x4){0.f, 0.f, 0.f, 0.f};
      #pragma unroll
      for (int kb = 0; kb < 2; ++kb) {
        s16x4 kf = *(const s16x4*)(k_lds + h3 * 2304 + (16 * nt + c) * 36 + 16 * kb + 4 * g);
        sc[nt] = mfma16(kf, qf16[kb][m], sc[nt]);
      }
    }
    const __hip_bfloat16* tb_ =
        tbl + (((win64 << 2) + h3) << 12) + (32 * mh + 16 * m + c) * 64;
    #pragma unroll
    for (int nt = 0; nt < 4; ++nt) {
      union { s16x4 v; __hip_bfloat16 h[4]; } tv;
      tv.v = *(const s16x4*)(tb_ + 16 * nt + 4 * g);
      #pragma unroll
      for (int r = 0; r < 4; ++r) sc[nt][r] += __bfloat162float(tv.h[r]);
    }
    float mx = -1e30f;
    #pragma unroll
    for (int nt = 0; nt < 4; ++nt)
      #pragma unroll
      for (int r = 0; r < 4; ++r) mx = fmaxf(mx, sc[nt][r]);
    mx = fmaxf(mx, __shfl_xor(mx, 16));
    mx = fmaxf(mx, __shfl_xor(mx, 32));
    float sum = 0.f;
    #pragma unroll
    for (int nt = 0; nt < 4; ++nt)
      #pragma unroll
      for (int r = 0; r < 4; ++r) {
        float e = __builtin_amdgcn_exp2f(sc[nt][r] - mx);
        sc[nt][r] = e;
        sum += e;
      }
    sum += __shfl_xor(sum, 16);
    sum += __shfl_xor(sum, 32);
    float inv = __builtin_amdgcn_rcpf(sum);
    #pragma unroll
    for (int nt = 0; nt < 4; ++nt) {
      union { s16x4 v; __hip_bfloat16 h[4]; } u;
      #pragma unroll
      for (int r = 0; r < 4; ++r) u.h[r] = __float2bfloat16(sc[nt][r] * inv);
      pf16[m][nt] = u.v;
    }
  }
  __syncthreads();   // b3: vt visible; all k reads done

  // ---- PV: O^T = V^T @ P^T (x16 MFMA), output d-on-regs, s-on-lanes ----
  f32x4 oacc[2][2];
  #pragma unroll
  for (int ntd = 0; ntd < 2; ++ntd) {
    s16x4 vf16[4];
    #pragma unroll
    for (int nt = 0; nt < 4; ++nt) {
      int row = h3 * 32 + 16 * ntd + c;               // row&15 == c
      int tb = (4 * nt + g) ^ c;
      vf16[nt] = *(const s16x4*)(vt_lds + row * 64 + tb * 4);
    }
    #pragma unroll
    for (int m = 0; m < 2; ++m) {
      oacc[m][ntd] = (f32x4){0.f, 0.f, 0.f, 0.f};
      #pragma unroll
      for (int nt = 0; nt < 4; ++nt)
        oacc[m][ntd] = mfma16(vf16[nt], pf16[m][nt], oacc[m][ntd]);
    }
  }
  // o scatter (packed b64; k region, safe post-b3)
  #pragma unroll
  for (int m = 0; m < 2; ++m)
    #pragma unroll
    for (int ntd = 0; ntd < 2; ++ntd) {
      union { s16x4 v; __hip_bfloat16 h[4]; } u;
      #pragma unroll
      for (int r = 0; r < 4; ++r) u.h[r] = __float2bfloat16(oacc[m][ntd][r]);
      *(s16x4*)(o_lds + (32 * mh + 16 * m + c) * 136 + 32 * h3 + 16 * ntd + 4 * g) = u.v;
    }
  __syncthreads();   // b4: o visible

  // ---- proj GEMM (n-major out -> float4 stores). wave owns n-tile wv ----
  {
    f32x4 pacc[4];
    #pragma unroll
    for (int mt = 0; mt < 4; ++mt) pacc[mt] = (f32x4){0.f, 0.f, 0.f, 0.f};
    #pragma unroll
    for (int kt = 0; kt < 4; ++kt) {
      s16x8 bfp = *(const s16x8*)(wprojT + (16 * wv + c) * 128 + kt * 32 + g * 8);
      #pragma unroll
      for (int mt = 0; mt < 4; ++mt) {
        s16x8 afo = *(const s16x8*)(o_lds + (16 * mt + c) * 136 + kt * 32 + g * 8);
        pacc[mt] = __builtin_amdgcn_mfma_f32_16x16x32_bf16(bfp, afo, pacc[mt], 0, 0, 0);
      }
    }
    float4 pb4 = *(const float4*)(proj_bias + 16 * wv + 4 * g);
    #pragma unroll
    for (int mt = 0; mt < 4; ++mt) {
      int s = 16 * mt + c;
      if (s < WSQ) {
        int i = s / 7, j = s - i * 7;
        int hh = wy * 7 + i + SHIFT_SZ; if (hh >= HW) hh -= HW;
        int ww = wx * 7 + j + SHIFT_SZ; if (ww >= HW) ww -= HW;
        float4 v;
        v.x = pacc[mt][0] + pb4.x;
        v.y = pacc[mt][1] + pb4.y;
        v.z = pacc[mt][2] + pb4.z;
        v.w = pacc[mt][3] + pb4.w;
        *(float4*)(out + ((b * HW + hh) * HW + ww) * CH + 16 * wv + 4 * g) = v;
      }
    }
  }
}

extern "C" void kernel_launch(void* const* d_in, const int* in_sizes, int n_in,
                              void* d_out, int out_size, void* d_ws, size_t ws_size,
                              hipStream_t stream) {
  const float* x            = (const float*)d_in[0];
  const float* qkv_kernel   = (const float*)d_in[1];
  const float* qkv_bias     = (const float*)d_in[2];
  const float* proj_kernel  = (const float*)d_in[3];
  const float* proj_bias    = (const float*)d_in[4];
  const float* rel_pos_tbl  = (const float*)d_in[5];
  float* out = (float*)d_out;

  __hip_bfloat16* wsb    = (__hip_bfloat16*)d_ws;
  __hip_bfloat16* wqkvT  = wsb;            // 49152 elems
  __hip_bfloat16* wprojT = wsb + 49152;    // 16384 elems
  __hip_bfloat16* tbl    = wsb + 65536;    // 1048576 elems

  prep_weights<<<dim3(192), dim3(256), 0, stream>>>(qkv_kernel, proj_kernel, wsb);
  prep_tbl<<<dim3(4096), dim3(256), 0, stream>>>(rel_pos_tbl, tbl);
  swin_attn<<<dim3(4096), dim3(512), 0, stream>>>(x, qkv_bias, proj_bias,
                                                  wqkvT, wprojT, tbl, out);
}